// Round 9
// baseline (173.852 us; speedup 1.0000x reference)
//
#include <hip/hip_runtime.h>
#include <hip/hip_bf16.h>

#define NN 2048

typedef unsigned int u32;
typedef unsigned short u16;
typedef unsigned char u8;

typedef __attribute__((ext_vector_type(8))) short short8;
typedef __attribute__((ext_vector_type(4))) float f32x4;

__device__ __forceinline__ float bflo(u32 u){ return __uint_as_float(u << 16); }
__device__ __forceinline__ float bfhi(u32 u){ return __uint_as_float(u & 0xffff0000u); }
__device__ __forceinline__ u16 f2bf(float f){
  __hip_bfloat16 h = __float2bfloat16(f);
  return *reinterpret_cast<u16*>(&h);
}

// Collapse attn_mask (B,R,N,N) int32 + key_padding (B,N) int32 into a combo byte
// per (b,n,m): bit r = attn_mask[b][r][n][m], bit 3 = key_padding[b][m].
__global__ __launch_bounds__(256)
void prep_k(const int* __restrict__ am, const int* __restrict__ kp,
            u8* __restrict__ cmb)
{
  const size_t tid  = (size_t)blockIdx.x * 256 + threadIdx.x;
  const size_t base = tid * 4;
  const int row = (int)(base >> 11);            // b*2048 + n
  const int m0  = (int)(base & 2047);
  const int b = row >> 11, n = row & 2047;
  const size_t e0 = (((size_t)(b*3) * NN) + n) * NN + m0;
  const int4 a0 = *reinterpret_cast<const int4*>(am + e0);
  const int4 a1 = *reinterpret_cast<const int4*>(am + e0 + (size_t)NN*NN);
  const int4 a2 = *reinterpret_cast<const int4*>(am + e0 + 2*(size_t)NN*NN);
  const int4 kv = *reinterpret_cast<const int4*>(kp + (size_t)b*NN + m0);
  const int a0v[4] = {a0.x,a0.y,a0.z,a0.w};
  const int a1v[4] = {a1.x,a1.y,a1.z,a1.w};
  const int a2v[4] = {a2.x,a2.y,a2.z,a2.w};
  const int kvv[4] = {kv.x,kv.y,kv.z,kv.w};
  uchar4 out;
  u8* o = (u8*)&out;
  #pragma unroll
  for (int i = 0; i < 4; ++i)
    o[i] = (u8)((a0v[i]?1:0) | (a1v[i]?2:0) | (a2v[i]?4:0) | (kvv[i]?8:0));
  *reinterpret_cast<uchar4*>(cmb + base) = out;
}

// MFMA GEMM: C[4096,512] = (A @ W + bias) * scale. BM=64 BN=128 BK=64, 4 waves.
template<bool SCATTER, bool ABF16, bool OUTF32>
__global__ __launch_bounds__(256)
void gemm_mfma(const void* __restrict__ Av, const float* __restrict__ W,
               const float* __restrict__ bias, void* __restrict__ Cd, float scale)
{
  __shared__ u16 As[64*64];    // [m][k]
  __shared__ u16 Ws[128*64];   // [n][k] (transposed W)

  const int t = threadIdx.x;
  const int lane = t & 63;
  const int w = t >> 6;
  const int g = lane >> 4, r15 = lane & 15;
  const int m0 = blockIdx.x * 64;
  const int n0 = blockIdx.y * 128;
  const int wn = w * 32;

  const f32x4 fz = {0.f,0.f,0.f,0.f};
  f32x4 acc[4][2] = {{fz,fz},{fz,fz},{fz,fz},{fz,fz}};

  for (int k0 = 0; k0 < 512; k0 += 64) {
    { // stage A tile 64 rows x 64 k
      const int row = t >> 2, kc = (t & 3) * 16;
      u32 pk[8];
      if constexpr (ABF16) {
        const u16* A = (const u16*)Av;
        const uint4 v0 = *reinterpret_cast<const uint4*>(A + (size_t)(m0+row)*512 + k0 + kc);
        const uint4 v1 = *reinterpret_cast<const uint4*>(A + (size_t)(m0+row)*512 + k0 + kc + 8);
        pk[0]=v0.x; pk[1]=v0.y; pk[2]=v0.z; pk[3]=v0.w;
        pk[4]=v1.x; pk[5]=v1.y; pk[6]=v1.z; pk[7]=v1.w;
      } else {
        const float* A = (const float*)Av;
        float f[16];
        #pragma unroll
        for (int q = 0; q < 4; ++q) {
          const float4 v = *reinterpret_cast<const float4*>(A + (size_t)(m0+row)*512 + k0 + kc + 4*q);
          f[4*q]=v.x; f[4*q+1]=v.y; f[4*q+2]=v.z; f[4*q+3]=v.w;
        }
        #pragma unroll
        for (int q = 0; q < 8; ++q)
          pk[q] = (u32)f2bf(f[2*q]) | ((u32)f2bf(f[2*q+1]) << 16);
      }
      const int s0 = (t & 3) * 2;
      uint4 w0, w1;
      w0.x=pk[0]; w0.y=pk[1]; w0.z=pk[2]; w0.w=pk[3];
      w1.x=pk[4]; w1.y=pk[5]; w1.z=pk[6]; w1.w=pk[7];
      *reinterpret_cast<uint4*>(&As[row*64 + (((s0  ) ^ (row&7)) << 3)]) = w0;
      *reinterpret_cast<uint4*>(&As[row*64 + (((s0+1) ^ (row&7)) << 3)]) = w1;
    }
    { // stage W tile 64 k-rows x 128 n -> Ws[n][k] transposed
      const int kr = t >> 2;
      const int ncb = (t & 3) * 32;
      const float* wrow = W + (size_t)(k0 + kr) * 512 + n0 + ncb;
      #pragma unroll
      for (int i = 0; i < 8; ++i) {
        const float4 wv = *reinterpret_cast<const float4*>(wrow + i*4);
        const float fv[4] = {wv.x, wv.y, wv.z, wv.w};
        #pragma unroll
        for (int j2 = 0; j2 < 4; ++j2) {
          const int n = ncb + i*4 + j2;
          Ws[n*64 + ((((kr>>3) ^ (n&7)) << 3) | (kr & 7))] = f2bf(fv[j2]);
        }
      }
    }
    __syncthreads();

    #pragma unroll
    for (int ks = 0; ks < 2; ++ks) {
      short8 bfr[2], afr[4];
      #pragma unroll
      for (int ni = 0; ni < 2; ++ni) {
        const int n = wn + 16*ni + r15;
        bfr[ni] = *reinterpret_cast<const short8*>(&Ws[n*64 + (((ks*4+g) ^ (n&7)) << 3)]);
      }
      #pragma unroll
      for (int mi = 0; mi < 4; ++mi) {
        const int m = 16*mi + r15;
        afr[mi] = *reinterpret_cast<const short8*>(&As[m*64 + (((ks*4+g) ^ (m&7)) << 3)]);
      }
      #pragma unroll
      for (int mi = 0; mi < 4; ++mi)
        #pragma unroll
        for (int ni = 0; ni < 2; ++ni)
          acc[mi][ni] = __builtin_amdgcn_mfma_f32_16x16x32_bf16(afr[mi], bfr[ni], acc[mi][ni], 0, 0, 0);
    }
    __syncthreads();
  }

  const float bia[2] = { bias[n0 + wn + r15], bias[n0 + wn + 16 + r15] };
  #pragma unroll
  for (int mi = 0; mi < 4; ++mi) {
    #pragma unroll
    for (int ni = 0; ni < 2; ++ni) {
      #pragma unroll
      for (int j = 0; j < 4; ++j) {
        const int row = m0 + 16*mi + 4*g + j;
        const int col = n0 + wn + 16*ni + r15;
        const float v = (acc[mi][ni][j] + bia[ni]) * scale;
        if constexpr (SCATTER) {
          const int bb = row & 1, ntok = row >> 1;
          const int h = col >> 6, c = col & 63;
          ((u16*)Cd)[(((size_t)(bb*8 + h) * NN + ntok) * 64) + c] = f2bf(v);
        } else if constexpr (OUTF32) {
          ((float*)Cd)[(size_t)row * 512 + col] = v;
        } else {
          ((u16*)Cd)[(size_t)row * 512 + col] = f2bf(v);
        }
      }
    }
  }
}

// MFMA flash attention with key-split. Q/K/V: [b*8+h][n][64] bf16, Q pre-scaled
// by 1/sqrt(64). grid (nq/64, 16, nsplit). If Opart!=null: write unnormalized
// f32 partials [s][bh][q][64] + Ml[s][bh][q]={m,l}; else normalize + bf16 Ob.
__global__ __launch_bounds__(256)
void attn_mfma(const u16* __restrict__ Q, const u16* __restrict__ K,
               const u16* __restrict__ V, const u8* __restrict__ cmb,
               const float* __restrict__ mw, u16* __restrict__ O,
               float* __restrict__ Opart, float2* __restrict__ Ml, int kspan)
{
  __shared__ u16 Ks[64*64];    // [key][ch], ch-slot(8) XOR (key&7)
  __shared__ u16 Vs[64*64];    // [ch][key], key-slot(8) XOR (ch&7)
  __shared__ u16 Ps[4][16*64]; // per wave: [q][key], key-slot(8) XOR (q&7)

  const int t = threadIdx.x;
  const int lane = t & 63;
  const int w = t >> 6;
  const int g = lane >> 4;
  const int r15 = lane & 15;
  const int bh = blockIdx.y;
  const int z = blockIdx.z;
  const int b = bh >> 3, h = bh & 7;
  const int n0 = blockIdx.x * 64;
  const int nq = n0 + w*16 + r15;
  const int k_beg = z * kspan;
  const float NEGINF = -__builtin_inff();

  const float mw0 = mw[h*4+0], mw1 = mw[h*4+1], mw2 = mw[h*4+2];
  const float msc = mw[h*4+3];
  const float mxw = fmaxf(mw0, fmaxf(mw1, mw2));
  const float e0 = __expf(mw0-mxw), e1 = __expf(mw1-mxw), e2 = __expf(mw2-mxw);
  const float inv = msc / (e0+e1+e2);
  const float rw0 = e0*inv, rw1 = e1*inv, rw2 = e2*inv;

  const u16* qrow = Q + ((size_t)bh*NN + nq)*64;
  const short8 bq0 = *reinterpret_cast<const short8*>(qrow + 8*g);
  const short8 bq1 = *reinterpret_cast<const short8*>(qrow + 32 + 8*g);

  const u8* crow = cmb + ((size_t)(b*NN + nq))*NN;

  float m_run = NEGINF, l_run = 0.f;
  const f32x4 fz = {0.f, 0.f, 0.f, 0.f};
  f32x4 oacc[4] = {fz, fz, fz, fz};

  const int sm  = t >> 2;
  const int sc0 = (t & 3) * 16;

  const int ntiles = kspan >> 6;
  for (int it = 0; it < ntiles; ++it) {
    const int m0 = k_beg + it * 64;
    __syncthreads();
    {
      const uint4* src = reinterpret_cast<const uint4*>(K + ((size_t)bh*NN + m0 + sm)*64 + sc0);
      uint4 k0v = src[0], k1v = src[1];
      const int s0 = sc0 >> 3;
      *reinterpret_cast<uint4*>(&Ks[sm*64 + (((s0    ) ^ (sm & 7)) << 3)]) = k0v;
      *reinterpret_cast<uint4*>(&Ks[sm*64 + (((s0 + 1) ^ (sm & 7)) << 3)]) = k1v;
    }
    {
      const uint4* src = reinterpret_cast<const uint4*>(V + ((size_t)bh*NN + m0 + sm)*64 + sc0);
      uint4 v0v = src[0], v1v = src[1];
      u16 e[16];
      e[0]=v0v.x&0xffff; e[1]=v0v.x>>16; e[2]=v0v.y&0xffff; e[3]=v0v.y>>16;
      e[4]=v0v.z&0xffff; e[5]=v0v.z>>16; e[6]=v0v.w&0xffff; e[7]=v0v.w>>16;
      e[8]=v1v.x&0xffff; e[9]=v1v.x>>16; e[10]=v1v.y&0xffff; e[11]=v1v.y>>16;
      e[12]=v1v.z&0xffff; e[13]=v1v.z>>16; e[14]=v1v.w&0xffff; e[15]=v1v.w>>16;
      #pragma unroll
      for (int i=0;i<16;++i){
        const int c = sc0 + i;
        Vs[c*64 + ((((sm>>3) ^ (c&7)) << 3) | (sm & 7))] = e[i];
      }
    }
    __syncthreads();

    f32x4 sac[4];
    #pragma unroll
    for (int kt = 0; kt < 4; ++kt) {
      const int key = 16*kt + r15;
      const short8 a0 = *reinterpret_cast<const short8*>(&Ks[key*64 + (((g  ) ^ (key&7)) << 3)]);
      const short8 a1 = *reinterpret_cast<const short8*>(&Ks[key*64 + (((g+4) ^ (key&7)) << 3)]);
      f32x4 s = fz;
      s = __builtin_amdgcn_mfma_f32_16x16x32_bf16(a0, bq0, s, 0, 0, 0);
      s = __builtin_amdgcn_mfma_f32_16x16x32_bf16(a1, bq1, s, 0, 0, 0);
      sac[kt] = s;
    }

    float sv[4][4];
    float pmax = NEGINF;
    #pragma unroll
    for (int kt = 0; kt < 4; ++kt) {
      const u32 cw = *reinterpret_cast<const u32*>(crow + m0 + 16*kt + 4*g);
      #pragma unroll
      for (int j = 0; j < 4; ++j) {
        const u32 ci = (cw >> (8*j)) & 0xffu;
        float x = sac[kt][j];
        x += (ci & 1) ? 0.f : rw0;
        x += (ci & 2) ? 0.f : rw1;
        x += (ci & 4) ? 0.f : rw2;
        sv[kt][j] = (ci & 8) ? NEGINF : x;
        pmax = fmaxf(pmax, sv[kt][j]);
      }
    }
    float tmax = pmax;
    tmax = fmaxf(tmax, __shfl_xor(tmax, 16));
    tmax = fmaxf(tmax, __shfl_xor(tmax, 32));

    const float nm = fmaxf(m_run, tmax);
    float sc;
    if (nm == NEGINF) { sc = 1.f; }
    else { sc = __expf(m_run - nm); m_run = nm; }

    float psum = 0.f;
    #pragma unroll
    for (int kt = 0; kt < 4; ++kt) {
      float p[4];
      #pragma unroll
      for (int j = 0; j < 4; ++j) {
        p[j] = (nm == NEGINF) ? 0.f : __expf(sv[kt][j] - nm);
        psum += p[j];
      }
      const int slot = 2*kt + (g >> 1);
      const int off  = 4 * (g & 1);
      *reinterpret_cast<ushort4*>(&Ps[w][r15*64 + ((slot ^ (r15 & 7)) << 3) + off]) =
        make_ushort4(f2bf(p[0]), f2bf(p[1]), f2bf(p[2]), f2bf(p[3]));
    }
    psum += __shfl_xor(psum, 16);
    psum += __shfl_xor(psum, 32);
    l_run = l_run * sc + psum;
    #pragma unroll
    for (int ct = 0; ct < 4; ++ct) oacc[ct] *= sc;

    __syncthreads();

    const short8 bp0 = *reinterpret_cast<const short8*>(&Ps[w][r15*64 + (((g  ) ^ (r15 & 7)) << 3)]);
    const short8 bp1 = *reinterpret_cast<const short8*>(&Ps[w][r15*64 + (((g+4) ^ (r15 & 7)) << 3)]);
    #pragma unroll
    for (int ct = 0; ct < 4; ++ct) {
      const int c = 16*ct + r15;
      const short8 av0 = *reinterpret_cast<const short8*>(&Vs[c*64 + (((g  ) ^ (c&7)) << 3)]);
      const short8 av1 = *reinterpret_cast<const short8*>(&Vs[c*64 + (((g+4) ^ (c&7)) << 3)]);
      oacc[ct] = __builtin_amdgcn_mfma_f32_16x16x32_bf16(av0, bp0, oacc[ct], 0, 0, 0);
      oacc[ct] = __builtin_amdgcn_mfma_f32_16x16x32_bf16(av1, bp1, oacc[ct], 0, 0, 0);
    }
  }

  if (Opart) {
    // partial: O^T frag rows c=16ct+4g+j at col q=r15 -> Opart[(z*16+bh)][nq][c]
    float* orow = Opart + (((size_t)(z*16 + bh)) * NN + nq) * 64;
    #pragma unroll
    for (int ct = 0; ct < 4; ++ct)
      *reinterpret_cast<float4*>(orow + 16*ct + 4*g) =
        make_float4(oacc[ct][0], oacc[ct][1], oacc[ct][2], oacc[ct][3]);
    if (g == 0)
      Ml[((size_t)(z*16 + bh)) * NN + nq] = make_float2(m_run, l_run);
  } else {
    const float rinv = 1.f / l_run;
    #pragma unroll
    for (int ct = 0; ct < 4; ++ct) {
      u16* dst = O + ((size_t)(nq*2 + b))*512 + h*64 + 16*ct + 4*g;
      *reinterpret_cast<ushort4*>(dst) =
        make_ushort4(f2bf(oacc[ct][0]*rinv), f2bf(oacc[ct][1]*rinv),
                     f2bf(oacc[ct][2]*rinv), f2bf(oacc[ct][3]*rinv));
    }
  }
}

// Merge split-K partials: wave = (bh, q), lane = channel.
__global__ __launch_bounds__(256)
void combine_k(const float* __restrict__ Opart, const float2* __restrict__ Ml,
               u16* __restrict__ Ob, int nsplit)
{
  const int t = threadIdx.x;
  const int lane = t & 63, w = t >> 6;
  const int q = blockIdx.x * 4 + w;
  const int bh = blockIdx.y;
  const int b = bh >> 3, h = bh & 7;

  float M = -__builtin_inff();
  for (int s = 0; s < nsplit; ++s)
    M = fmaxf(M, Ml[((size_t)(s*16 + bh)) * NN + q].x);

  float num = 0.f, den = 0.f;
  for (int s = 0; s < nsplit; ++s) {
    const float2 ml = Ml[((size_t)(s*16 + bh)) * NN + q];
    const float ws = (ml.x == -__builtin_inff()) ? 0.f : __expf(ml.x - M);
    den += ws * ml.y;
    num += ws * Opart[(((size_t)(s*16 + bh)) * NN + q) * 64 + lane];
  }
  const float r = (den > 0.f) ? num / den : 0.f;
  Ob[((size_t)(q*2 + b)) * 512 + h*64 + lane] = f2bf(r);
}

extern "C" void kernel_launch(void* const* d_in, const int* in_sizes, int n_in,
                              void* d_out, int out_size, void* d_ws, size_t ws_size,
                              hipStream_t stream)
{
  const float* xq = (const float*)d_in[0];
  const float* xk = (const float*)d_in[1];
  const float* xv = (const float*)d_in[2];
  const int*   am = (const int*)d_in[3];
  const int*   kp = (const int*)d_in[4];
  const float* Wq = (const float*)d_in[5];
  const float* bq = (const float*)d_in[6];
  const float* Wk = (const float*)d_in[7];
  const float* bk = (const float*)d_in[8];
  const float* Wv = (const float*)d_in[9];
  const float* bv = (const float*)d_in[10];
  const float* Wo = (const float*)d_in[11];
  const float* bo = (const float*)d_in[12];
  const float* mw = (const float*)d_in[13];

  u16* Qb = (u16*)d_ws;                       // [16][2048][64] bf16, 4 MB
  u16* Kb = Qb + (size_t)16*NN*64;
  u16* Vb = Kb + (size_t)16*NN*64;
  u16* Ob = Vb + (size_t)16*NN*64;            // [4096][512] bf16, 4 MB
  u8*  cmb = (u8*)(Ob + (size_t)4096*512);    // [2][2048][2048] bytes, 8 MB
  float* Opart = (float*)(cmb + (size_t)2*NN*NN);

  const size_t base_bytes = (size_t)(Opart - (float*)d_ws) * 4;
  int nsplit = 1;
  for (int s = 4; s >= 1; s >>= 1) {
    const size_t need = base_bytes + (size_t)s * 16 * NN * (64*4 + 8);
    if (need <= ws_size) { nsplit = s; break; }
  }
  float2* Ml = (float2*)(Opart + (size_t)nsplit * 16 * NN * 64);
  const bool split = (base_bytes + (size_t)16*NN*(64*4+8) <= ws_size);

  prep_k<<<(2*NN*NN/4 + 255)/256, 256, 0, stream>>>(am, kp, cmb);

  dim3 gg(64, 4);
  gemm_mfma<true , false, false><<<gg, 256, 0, stream>>>(xq, Wq, bq, Qb, 0.125f);
  gemm_mfma<true , false, false><<<gg, 256, 0, stream>>>(xk, Wk, bk, Kb, 1.0f);
  gemm_mfma<true , false, false><<<gg, 256, 0, stream>>>(xv, Wv, bv, Vb, 1.0f);

  if (split) {
    attn_mfma<<<dim3(32, 16, nsplit), 256, 0, stream>>>(Qb, Kb, Vb, cmb, mw, Ob,
                                                        Opart, Ml, NN / nsplit);
    combine_k<<<dim3(NN/4, 16), 256, 0, stream>>>(Opart, Ml, Ob, nsplit);
  } else {
    attn_mfma<<<dim3(32, 16, 1), 256, 0, stream>>>(Qb, Kb, Vb, cmb, mw, Ob,
                                                   nullptr, nullptr, NN);
  }

  gemm_mfma<false, true , true ><<<gg, 256, 0, stream>>>(Ob, Wo, bo, d_out, 1.0f);
}

// Round 10
// 169.776 us; speedup vs baseline: 1.0240x; 1.0240x over previous
//
#include <hip/hip_runtime.h>
#include <hip/hip_bf16.h>

#define NN 2048
#define LOG2E 1.4426950408889634f

typedef unsigned int u32;
typedef unsigned short u16;
typedef unsigned char u8;

typedef __attribute__((ext_vector_type(8))) short short8;
typedef __attribute__((ext_vector_type(4))) float f32x4;

__device__ __forceinline__ u16 f2bf(float f){
  __hip_bfloat16 h = __float2bfloat16(f);
  return *reinterpret_cast<u16*>(&h);
}

// Collapse attn_mask (B,R,N,N) int32 + key_padding (B,N) int32 into a combo byte
// per (b,n,m): bit r = attn_mask[b][r][n][m], bit 3 = key_padding[b][m].
__global__ __launch_bounds__(256)
void prep_k(const int* __restrict__ am, const int* __restrict__ kp,
            u8* __restrict__ cmb)
{
  const size_t tid  = (size_t)blockIdx.x * 256 + threadIdx.x;
  const size_t base = tid * 4;
  const int row = (int)(base >> 11);            // b*2048 + n
  const int m0  = (int)(base & 2047);
  const int b = row >> 11, n = row & 2047;
  const size_t e0 = (((size_t)(b*3) * NN) + n) * NN + m0;
  const int4 a0 = *reinterpret_cast<const int4*>(am + e0);
  const int4 a1 = *reinterpret_cast<const int4*>(am + e0 + (size_t)NN*NN);
  const int4 a2 = *reinterpret_cast<const int4*>(am + e0 + 2*(size_t)NN*NN);
  const int4 kv = *reinterpret_cast<const int4*>(kp + (size_t)b*NN + m0);
  const int a0v[4] = {a0.x,a0.y,a0.z,a0.w};
  const int a1v[4] = {a1.x,a1.y,a1.z,a1.w};
  const int a2v[4] = {a2.x,a2.y,a2.z,a2.w};
  const int kvv[4] = {kv.x,kv.y,kv.z,kv.w};
  uchar4 out;
  u8* o = (u8*)&out;
  #pragma unroll
  for (int i = 0; i < 4; ++i)
    o[i] = (u8)((a0v[i]?1:0) | (a1v[i]?2:0) | (a2v[i]?4:0) | (kvv[i]?8:0));
  *reinterpret_cast<uchar4*>(cmb + base) = out;
}

// Convert f32 x arrays -> bf16 (packed). grid (1024, 3).
__global__ __launch_bounds__(256)
void convx_k(const float* __restrict__ s0, const float* __restrict__ s1,
             const float* __restrict__ s2, u16* __restrict__ dst)
{
  const int z = blockIdx.y;
  const float* src = (z == 0) ? s0 : (z == 1) ? s1 : s2;
  const size_t i8 = ((size_t)blockIdx.x * 256 + threadIdx.x) * 8;
  const float4 a = *reinterpret_cast<const float4*>(src + i8);
  const float4 b = *reinterpret_cast<const float4*>(src + i8 + 4);
  uint4 o;
  o.x = (u32)f2bf(a.x) | ((u32)f2bf(a.y) << 16);
  o.y = (u32)f2bf(a.z) | ((u32)f2bf(a.w) << 16);
  o.z = (u32)f2bf(b.x) | ((u32)f2bf(b.y) << 16);
  o.w = (u32)f2bf(b.z) | ((u32)f2bf(b.w) << 16);
  *reinterpret_cast<uint4*>(dst + (size_t)z * 2097152 + i8) = o;
}

// Transpose W f32 [512][512] -> bf16 W^T [n][k]. grid (16,16), block 256.
__global__ __launch_bounds__(256)
void trw_k(const float* __restrict__ W, u16* __restrict__ WT)
{
  __shared__ float tile[32][33];
  const int t = threadIdx.x;
  const int k0 = blockIdx.x * 32, n0 = blockIdx.y * 32;
  const int c = t & 31, r = t >> 5;
  #pragma unroll
  for (int i = 0; i < 4; ++i)
    tile[r + 8*i][c] = W[(size_t)(k0 + r + 8*i) * 512 + n0 + c];
  __syncthreads();
  #pragma unroll
  for (int i = 0; i < 4; ++i)
    WT[(size_t)(n0 + r + 8*i) * 512 + k0 + c] = f2bf(tile[c][r + 8*i]);
}

// MFMA GEMM: C[4096,512] = (A(bf16) @ W^T(bf16,[n][k]) + bias) * scale.
// BM=64 BN=128 BK=64, 4 waves; all-vectorized staging.
template<bool SCATTER, bool OUTF32>
__global__ __launch_bounds__(256)
void gemm_bb(const u16* __restrict__ A, const u16* __restrict__ WT,
             const float* __restrict__ bias, void* __restrict__ Cd, float scale)
{
  __shared__ u16 As[64*64];    // [m][k], 8-slot XOR (m&7)
  __shared__ u16 Ws[128*64];   // [n][k], 8-slot XOR (n&7)

  const int t = threadIdx.x;
  const int lane = t & 63;
  const int w = t >> 6;
  const int g = lane >> 4, r15 = lane & 15;
  const int m0 = blockIdx.x * 64;
  const int n0 = blockIdx.y * 128;
  const int wn = w * 32;

  const f32x4 fz = {0.f,0.f,0.f,0.f};
  f32x4 acc[4][2] = {{fz,fz},{fz,fz},{fz,fz},{fz,fz}};

  for (int k0 = 0; k0 < 512; k0 += 64) {
    { // A: 64x64, 2 uint4/thread
      const int row = t >> 2, kc = (t & 3) * 16, s0 = (t & 3) * 2;
      const uint4 v0 = *reinterpret_cast<const uint4*>(A + (size_t)(m0+row)*512 + k0 + kc);
      const uint4 v1 = *reinterpret_cast<const uint4*>(A + (size_t)(m0+row)*512 + k0 + kc + 8);
      *reinterpret_cast<uint4*>(&As[row*64 + (((s0  ) ^ (row&7)) << 3)]) = v0;
      *reinterpret_cast<uint4*>(&As[row*64 + (((s0+1) ^ (row&7)) << 3)]) = v1;
    }
    { // W^T: 128x64, 4 uint4/thread
      const int rn = t >> 1, kc = (t & 1) * 32, sb = (t & 1) * 4;
      #pragma unroll
      for (int i = 0; i < 4; ++i) {
        const uint4 v = *reinterpret_cast<const uint4*>(WT + (size_t)(n0+rn)*512 + k0 + kc + 8*i);
        *reinterpret_cast<uint4*>(&Ws[rn*64 + (((sb + i) ^ (rn&7)) << 3)]) = v;
      }
    }
    __syncthreads();

    #pragma unroll
    for (int ks = 0; ks < 2; ++ks) {
      short8 bfr[2], afr[4];
      #pragma unroll
      for (int ni = 0; ni < 2; ++ni) {
        const int n = wn + 16*ni + r15;
        bfr[ni] = *reinterpret_cast<const short8*>(&Ws[n*64 + (((ks*4+g) ^ (n&7)) << 3)]);
      }
      #pragma unroll
      for (int mi = 0; mi < 4; ++mi) {
        const int m = 16*mi + r15;
        afr[mi] = *reinterpret_cast<const short8*>(&As[m*64 + (((ks*4+g) ^ (m&7)) << 3)]);
      }
      #pragma unroll
      for (int mi = 0; mi < 4; ++mi)
        #pragma unroll
        for (int ni = 0; ni < 2; ++ni)
          acc[mi][ni] = __builtin_amdgcn_mfma_f32_16x16x32_bf16(afr[mi], bfr[ni], acc[mi][ni], 0, 0, 0);
    }
    __syncthreads();
  }

  const float bia[2] = { bias[n0 + wn + r15], bias[n0 + wn + 16 + r15] };
  #pragma unroll
  for (int mi = 0; mi < 4; ++mi) {
    #pragma unroll
    for (int ni = 0; ni < 2; ++ni) {
      #pragma unroll
      for (int j = 0; j < 4; ++j) {
        const int row = m0 + 16*mi + 4*g + j;
        const int col = n0 + wn + 16*ni + r15;
        const float v = (acc[mi][ni][j] + bia[ni]) * scale;
        if constexpr (SCATTER) {
          const int bb = row & 1, ntok = row >> 1;
          const int h = col >> 6, c = col & 63;
          ((u16*)Cd)[(((size_t)(bb*8 + h) * NN + ntok) * 64) + c] = f2bf(v);
        } else if constexpr (OUTF32) {
          ((float*)Cd)[(size_t)row * 512 + col] = v;
        } else {
          ((u16*)Cd)[(size_t)row * 512 + col] = f2bf(v);
        }
      }
    }
  }
}

// MFMA flash attention, 8 waves / 128 queries per block, split-K, exp2 domain.
// Q pre-scaled by 0.125*log2e. grid (16, 16, nsplit).
__global__ __launch_bounds__(512)
void attn_mfma(const u16* __restrict__ Q, const u16* __restrict__ K,
               const u16* __restrict__ V, const u8* __restrict__ cmb,
               const float* __restrict__ mw, u16* __restrict__ O,
               float* __restrict__ Opart, float2* __restrict__ Ml, int kspan)
{
  __shared__ u16 Ks[64*64];     // [key][ch], ch-slot(8) XOR (key&7)
  __shared__ u16 Vs[64*64];     // [ch][key], key-slot(8) XOR (ch&7)
  __shared__ u16 Ps[8][16*64];  // per wave: [q][key], key-slot(8) XOR (q&7)
  __shared__ float lut[16];     // rel-bias (log2 units), -inf for padded

  const int t = threadIdx.x;
  const int lane = t & 63;
  const int w = t >> 6;
  const int g = lane >> 4;
  const int r15 = lane & 15;
  const int bh = blockIdx.y;
  const int z = blockIdx.z;
  const int b = bh >> 3, h = bh & 7;
  const int n0 = blockIdx.x * 128;
  const int nq = n0 + w*16 + r15;
  const int k_beg = z * kspan;
  const float NEGINF = -__builtin_inff();

  if (t < 16) {
    const float mw0 = mw[h*4+0], mw1 = mw[h*4+1], mw2 = mw[h*4+2];
    const float msc = mw[h*4+3];
    const float mxw = fmaxf(mw0, fmaxf(mw1, mw2));
    const float e0 = __expf(mw0-mxw), e1 = __expf(mw1-mxw), e2 = __expf(mw2-mxw);
    const float inv = msc / (e0+e1+e2);
    float v = ((t & 1) ? 0.f : e0*inv) + ((t & 2) ? 0.f : e1*inv)
            + ((t & 4) ? 0.f : e2*inv);
    lut[t] = (t & 8) ? NEGINF : v * LOG2E;
  }

  const u16* qrow = Q + ((size_t)bh*NN + nq)*64;
  const short8 bq0 = *reinterpret_cast<const short8*>(qrow + 8*g);
  const short8 bq1 = *reinterpret_cast<const short8*>(qrow + 32 + 8*g);

  const u8* crow = cmb + ((size_t)(b*NN + nq))*NN;

  float m_run = NEGINF, l_run = 0.f;
  const f32x4 fz = {0.f, 0.f, 0.f, 0.f};
  f32x4 oacc[4] = {fz, fz, fz, fz};

  const int sm  = t >> 3;          // staging key row 0..63
  const int sc0 = (t & 7) * 8;     // staging ch base
  const int ss  = t & 7;           // staging slot

  const int ntiles = kspan >> 6;
  for (int it = 0; it < ntiles; ++it) {
    const int m0 = k_beg + it * 64;
    __syncthreads();
    { // stage K (1 uint4/thread)
      const uint4 kv = *reinterpret_cast<const uint4*>(K + ((size_t)bh*NN + m0 + sm)*64 + sc0);
      *reinterpret_cast<uint4*>(&Ks[sm*64 + ((ss ^ (sm & 7)) << 3)]) = kv;
    }
    { // stage V transposed (8 scalar writes/thread)
      const uint4 vv = *reinterpret_cast<const uint4*>(V + ((size_t)bh*NN + m0 + sm)*64 + sc0);
      u16 e[8];
      e[0]=vv.x&0xffff; e[1]=vv.x>>16; e[2]=vv.y&0xffff; e[3]=vv.y>>16;
      e[4]=vv.z&0xffff; e[5]=vv.z>>16; e[6]=vv.w&0xffff; e[7]=vv.w>>16;
      #pragma unroll
      for (int i = 0; i < 8; ++i) {
        const int c = sc0 + i;
        Vs[c*64 + ((((sm>>3) ^ (c&7)) << 3) | (sm & 7))] = e[i];
      }
    }
    __syncthreads();

    // S^T = K @ Q^T
    f32x4 sac[4];
    #pragma unroll
    for (int kt = 0; kt < 4; ++kt) {
      const int key = 16*kt + r15;
      const short8 a0 = *reinterpret_cast<const short8*>(&Ks[key*64 + (((g  ) ^ (key&7)) << 3)]);
      const short8 a1 = *reinterpret_cast<const short8*>(&Ks[key*64 + (((g+4) ^ (key&7)) << 3)]);
      f32x4 s = fz;
      s = __builtin_amdgcn_mfma_f32_16x16x32_bf16(a0, bq0, s, 0, 0, 0);
      s = __builtin_amdgcn_mfma_f32_16x16x32_bf16(a1, bq1, s, 0, 0, 0);
      sac[kt] = s;
    }

    // bias via LUT + lane-local max (log2 domain)
    float sv[4][4];
    float pmax = NEGINF;
    #pragma unroll
    for (int kt = 0; kt < 4; ++kt) {
      const u32 cw = *reinterpret_cast<const u32*>(crow + m0 + 16*kt + 4*g);
      #pragma unroll
      for (int j = 0; j < 4; ++j) {
        const u32 ci = (cw >> (8*j)) & 0xffu;
        sv[kt][j] = sac[kt][j] + lut[ci];
        pmax = fmaxf(pmax, sv[kt][j]);
      }
    }
    float tmax = pmax;
    tmax = fmaxf(tmax, __shfl_xor(tmax, 16));
    tmax = fmaxf(tmax, __shfl_xor(tmax, 32));

    const float nm = fmaxf(m_run, tmax);
    float sc;
    if (nm == NEGINF) { sc = 1.f; }
    else { sc = exp2f(m_run - nm); m_run = nm; }

    float psum = 0.f;
    #pragma unroll
    for (int kt = 0; kt < 4; ++kt) {
      float p[4];
      #pragma unroll
      for (int j = 0; j < 4; ++j) {
        p[j] = (nm == NEGINF) ? 0.f : exp2f(sv[kt][j] - nm);
        psum += p[j];
      }
      const int slot = 2*kt + (g >> 1);
      const int off  = 4 * (g & 1);
      *reinterpret_cast<ushort4*>(&Ps[w][r15*64 + ((slot ^ (r15 & 7)) << 3) + off]) =
        make_ushort4(f2bf(p[0]), f2bf(p[1]), f2bf(p[2]), f2bf(p[3]));
    }
    psum += __shfl_xor(psum, 16);
    psum += __shfl_xor(psum, 32);
    l_run = l_run * sc + psum;
    #pragma unroll
    for (int ct = 0; ct < 4; ++ct) oacc[ct] *= sc;

    __syncthreads();

    // O^T += V^T @ P^T
    const short8 bp0 = *reinterpret_cast<const short8*>(&Ps[w][r15*64 + (((g  ) ^ (r15 & 7)) << 3)]);
    const short8 bp1 = *reinterpret_cast<const short8*>(&Ps[w][r15*64 + (((g+4) ^ (r15 & 7)) << 3)]);
    #pragma unroll
    for (int ct = 0; ct < 4; ++ct) {
      const int c = 16*ct + r15;
      const short8 av0 = *reinterpret_cast<const short8*>(&Vs[c*64 + (((g  ) ^ (c&7)) << 3)]);
      const short8 av1 = *reinterpret_cast<const short8*>(&Vs[c*64 + (((g+4) ^ (c&7)) << 3)]);
      oacc[ct] = __builtin_amdgcn_mfma_f32_16x16x32_bf16(av0, bp0, oacc[ct], 0, 0, 0);
      oacc[ct] = __builtin_amdgcn_mfma_f32_16x16x32_bf16(av1, bp1, oacc[ct], 0, 0, 0);
    }
  }

  if (Opart) {
    float* orow = Opart + (((size_t)(z*16 + bh)) * NN + nq) * 64;
    #pragma unroll
    for (int ct = 0; ct < 4; ++ct)
      *reinterpret_cast<float4*>(orow + 16*ct + 4*g) =
        make_float4(oacc[ct][0], oacc[ct][1], oacc[ct][2], oacc[ct][3]);
    if (g == 0)
      Ml[((size_t)(z*16 + bh)) * NN + nq] = make_float2(m_run, l_run);
  } else {
    const float rinv = 1.f / l_run;
    #pragma unroll
    for (int ct = 0; ct < 4; ++ct) {
      u16* dst = O + ((size_t)(nq*2 + b))*512 + h*64 + 16*ct + 4*g;
      *reinterpret_cast<ushort4*>(dst) =
        make_ushort4(f2bf(oacc[ct][0]*rinv), f2bf(oacc[ct][1]*rinv),
                     f2bf(oacc[ct][2]*rinv), f2bf(oacc[ct][3]*rinv));
    }
  }
}

// Merge split-K partials (log2-domain m). wave = (bh, q), lane = channel.
__global__ __launch_bounds__(256)
void combine_k(const float* __restrict__ Opart, const float2* __restrict__ Ml,
               u16* __restrict__ Ob, int nsplit)
{
  const int t = threadIdx.x;
  const int lane = t & 63, w = t >> 6;
  const int q = blockIdx.x * 4 + w;
  const int bh = blockIdx.y;
  const int b = bh >> 3, h = bh & 7;

  float M = -__builtin_inff();
  for (int s = 0; s < nsplit; ++s)
    M = fmaxf(M, Ml[((size_t)(s*16 + bh)) * NN + q].x);

  float num = 0.f, den = 0.f;
  for (int s = 0; s < nsplit; ++s) {
    const float2 ml = Ml[((size_t)(s*16 + bh)) * NN + q];
    const float ws = (ml.x == -__builtin_inff()) ? 0.f : exp2f(ml.x - M);
    den += ws * ml.y;
    num += ws * Opart[(((size_t)(s*16 + bh)) * NN + q) * 64 + lane];
  }
  const float r = (den > 0.f) ? num / den : 0.f;
  Ob[((size_t)(q*2 + b)) * 512 + h*64 + lane] = f2bf(r);
}

extern "C" void kernel_launch(void* const* d_in, const int* in_sizes, int n_in,
                              void* d_out, int out_size, void* d_ws, size_t ws_size,
                              hipStream_t stream)
{
  const float* xq = (const float*)d_in[0];
  const float* xk = (const float*)d_in[1];
  const float* xv = (const float*)d_in[2];
  const int*   am = (const int*)d_in[3];
  const int*   kp = (const int*)d_in[4];
  const float* Wq = (const float*)d_in[5];
  const float* bq = (const float*)d_in[6];
  const float* Wk = (const float*)d_in[7];
  const float* bk = (const float*)d_in[8];
  const float* Wv = (const float*)d_in[9];
  const float* bv = (const float*)d_in[10];
  const float* Wo = (const float*)d_in[11];
  const float* bo = (const float*)d_in[12];
  const float* mw = (const float*)d_in[13];

  u16* Qb = (u16*)d_ws;                       // [16][2048][64] bf16, 4 MB
  u16* Kb = Qb + (size_t)16*NN*64;
  u16* Vb = Kb + (size_t)16*NN*64;
  u16* Ob = Vb + (size_t)16*NN*64;            // [4096][512] bf16, 4 MB
  u8*  cmb = (u8*)(Ob + (size_t)4096*512);    // [2][2048][2048] bytes, 8 MB
  u8*  R   = cmb + (size_t)2*NN*NN;           // scratch region (aliased)

  // prepass views (dead once attn starts writing Opart)
  u16* xb  = (u16*)R;                         // 3 x [4096][512] bf16, 12 MB
  u16* WT3 = xb + (size_t)3*4096*512;         // 3 x [512][512] bf16, 1.5 MB
  // split-K views
  float* Opart = (float*)R;
  const size_t base_bytes = (size_t)(R - (u8*)d_ws);
  int nsplit = 1;
  for (int s = 4; s >= 1; s >>= 1) {
    const size_t need = base_bytes + (size_t)s * 16 * NN * (64*4 + 8);
    if (need <= ws_size) { nsplit = s; break; }
  }
  float2* Ml = (float2*)(Opart + (size_t)nsplit * 16 * NN * 64);
  const size_t pre_need = base_bytes + (size_t)3*4096*512*2 + (size_t)3*512*512*2;
  const bool split = (base_bytes + (size_t)16*NN*(64*4+8) <= ws_size) &&
                     (pre_need <= ws_size);
  u16* WTo = Qb;                              // reuse Qb after attn (0.5 MB)

  prep_k<<<(2*NN*NN/4 + 255)/256, 256, 0, stream>>>(am, kp, cmb);
  convx_k<<<dim3(1024, 3), 256, 0, stream>>>(xq, xk, xv, xb);
  trw_k<<<dim3(16, 16), 256, 0, stream>>>(Wq, WT3);
  trw_k<<<dim3(16, 16), 256, 0, stream>>>(Wk, WT3 + 262144);
  trw_k<<<dim3(16, 16), 256, 0, stream>>>(Wv, WT3 + 2*262144);

  dim3 gg(64, 4);
  const float qscale = 0.125f * LOG2E;
  gemm_bb<true , false><<<gg, 256, 0, stream>>>(xb,            WT3,          bq, Qb, qscale);
  gemm_bb<true , false><<<gg, 256, 0, stream>>>(xb + 2097152,  WT3+262144,   bk, Kb, 1.0f);
  gemm_bb<true , false><<<gg, 256, 0, stream>>>(xb + 2*2097152,WT3+2*262144, bv, Vb, 1.0f);

  if (split) {
    attn_mfma<<<dim3(16, 16, nsplit), 512, 0, stream>>>(Qb, Kb, Vb, cmb, mw, Ob,
                                                        Opart, Ml, NN / nsplit);
    combine_k<<<dim3(NN/4, 16), 256, 0, stream>>>(Opart, Ml, Ob, nsplit);
    trw_k<<<dim3(16, 16), 256, 0, stream>>>(Wo, WTo);
    gemm_bb<false, true ><<<gg, 256, 0, stream>>>(Ob, WTo, bo, d_out, 1.0f);
  } else {
    // fallback: no-split attention; transpose Wo into WT3 slot (still live-free)
    attn_mfma<<<dim3(16, 16, 1), 512, 0, stream>>>(Qb, Kb, Vb, cmb, mw, Ob,
                                                   nullptr, nullptr, NN);
    trw_k<<<dim3(16, 16), 256, 0, stream>>>(Wo, WTo);
    gemm_bb<false, true ><<<gg, 256, 0, stream>>>(Ob, WTo, bo, d_out, 1.0f);
  }
}

// Round 11
// 130.543 us; speedup vs baseline: 1.3318x; 1.3005x over previous
//
#include <hip/hip_runtime.h>
#include <hip/hip_bf16.h>

#define NN 2048
#define LOG2E 1.4426950408889634f

typedef unsigned int u32;
typedef unsigned short u16;
typedef unsigned char u8;

typedef __attribute__((ext_vector_type(8))) short short8;
typedef __attribute__((ext_vector_type(4))) float f32x4;

__device__ __forceinline__ u16 f2bf(float f){
  __hip_bfloat16 h = __float2bfloat16(f);
  return *reinterpret_cast<u16*>(&h);
}
__device__ __forceinline__ u32 pack2(float a, float b){
  return (u32)f2bf(a) | ((u32)f2bf(b) << 16);
}

// Collapse attn_mask (B,R,N,N) int32 + key_padding (B,N) int32 into a combo byte
// per (b,n,m): bit r = attn_mask[b][r][n][m], bit 3 = key_padding[b][m].
__global__ __launch_bounds__(256)
void prep_k(const int* __restrict__ am, const int* __restrict__ kp,
            u8* __restrict__ cmb)
{
  const size_t tid  = (size_t)blockIdx.x * 256 + threadIdx.x;
  const size_t base = tid * 4;
  const int row = (int)(base >> 11);            // b*2048 + n
  const int m0  = (int)(base & 2047);
  const int b = row >> 11, n = row & 2047;
  const size_t e0 = (((size_t)(b*3) * NN) + n) * NN + m0;
  const int4 a0 = *reinterpret_cast<const int4*>(am + e0);
  const int4 a1 = *reinterpret_cast<const int4*>(am + e0 + (size_t)NN*NN);
  const int4 a2 = *reinterpret_cast<const int4*>(am + e0 + 2*(size_t)NN*NN);
  const int4 kv = *reinterpret_cast<const int4*>(kp + (size_t)b*NN + m0);
  const int a0v[4] = {a0.x,a0.y,a0.z,a0.w};
  const int a1v[4] = {a1.x,a1.y,a1.z,a1.w};
  const int a2v[4] = {a2.x,a2.y,a2.z,a2.w};
  const int kvv[4] = {kv.x,kv.y,kv.z,kv.w};
  uchar4 out;
  u8* o = (u8*)&out;
  #pragma unroll
  for (int i = 0; i < 4; ++i)
    o[i] = (u8)((a0v[i]?1:0) | (a1v[i]?2:0) | (a2v[i]?4:0) | (kvv[i]?8:0));
  *reinterpret_cast<uchar4*>(cmb + base) = out;
}

// Transpose W f32 [512][512] -> bf16 W^T [n][k]. grid (16,16), block 256.
__global__ __launch_bounds__(256)
void trw_k(const float* __restrict__ W, u16* __restrict__ WT)
{
  __shared__ float tile[32][33];
  const int t = threadIdx.x;
  const int k0 = blockIdx.x * 32, n0 = blockIdx.y * 32;
  const int c = t & 31, r = t >> 5;
  #pragma unroll
  for (int i = 0; i < 4; ++i)
    tile[r + 8*i][c] = W[(size_t)(k0 + r + 8*i) * 512 + n0 + c];
  __syncthreads();
  #pragma unroll
  for (int i = 0; i < 4; ++i)
    WT[(size_t)(n0 + r + 8*i) * 512 + k0 + c] = f2bf(tile[c][r + 8*i]);
}

// Double-buffered MFMA GEMM core: C[64 x BN block] = (A @ W^T + bias)*scale.
// BM=64, BK=64, 4 waves; 1 barrier per k-tile; loads for tile t+1 issued
// before computing tile t.
template<int BN, bool SCATTER, bool ABF16, bool OUTF32>
__device__ __forceinline__
void gemm_core(const void* __restrict__ Av, const u16* __restrict__ WT,
               const float* __restrict__ bias, void* __restrict__ Cd,
               float scale, int m0, int n0)
{
  constexpr int NI  = BN / 64;   // frag cols per wave
  constexpr int WNL = BN / 32;   // W uint4 loads per thread
  __shared__ u16 As[2][64*64];
  __shared__ u16 Ws[2][BN*64];

  const int t = threadIdx.x;
  const int lane = t & 63;
  const int w = t >> 6;
  const int g = lane >> 4, r15 = lane & 15;
  const int wn = w * (BN/4);

  const int arow = t >> 2, akc = (t & 3) * 16, as0 = (t & 3) * 2;
  const int wrn = (BN==128) ? (t>>1) : (t>>2);
  const int wkc = (BN==128) ? ((t&1)*32) : ((t&3)*16);
  const int wsb = (BN==128) ? ((t&1)*4)  : ((t&3)*2);

  uint4  war[WNL];
  uint4  aab[2];
  float4 aaf[4];

  auto loadA = [&](int k0){
    if constexpr (ABF16) {
      const u16* A = (const u16*)Av;
      aab[0] = *reinterpret_cast<const uint4*>(A + (size_t)(m0+arow)*512 + k0 + akc);
      aab[1] = *reinterpret_cast<const uint4*>(A + (size_t)(m0+arow)*512 + k0 + akc + 8);
    } else {
      const float* A = (const float*)Av;
      #pragma unroll
      for (int q = 0; q < 4; ++q)
        aaf[q] = *reinterpret_cast<const float4*>(A + (size_t)(m0+arow)*512 + k0 + akc + 4*q);
    }
  };
  auto loadW = [&](int k0){
    #pragma unroll
    for (int i = 0; i < WNL; ++i)
      war[i] = *reinterpret_cast<const uint4*>(WT + (size_t)(n0+wrn)*512 + k0 + wkc + 8*i);
  };
  auto writeA = [&](int bf){
    uint4 v0, v1;
    if constexpr (ABF16) { v0 = aab[0]; v1 = aab[1]; }
    else {
      v0.x = pack2(aaf[0].x, aaf[0].y); v0.y = pack2(aaf[0].z, aaf[0].w);
      v0.z = pack2(aaf[1].x, aaf[1].y); v0.w = pack2(aaf[1].z, aaf[1].w);
      v1.x = pack2(aaf[2].x, aaf[2].y); v1.y = pack2(aaf[2].z, aaf[2].w);
      v1.z = pack2(aaf[3].x, aaf[3].y); v1.w = pack2(aaf[3].z, aaf[3].w);
    }
    *reinterpret_cast<uint4*>(&As[bf][arow*64 + (((as0  ) ^ (arow&7)) << 3)]) = v0;
    *reinterpret_cast<uint4*>(&As[bf][arow*64 + (((as0+1) ^ (arow&7)) << 3)]) = v1;
  };
  auto writeW = [&](int bf){
    #pragma unroll
    for (int i = 0; i < WNL; ++i)
      *reinterpret_cast<uint4*>(&Ws[bf][wrn*64 + (((wsb+i) ^ (wrn&7)) << 3)]) = war[i];
  };

  const f32x4 fz = {0.f,0.f,0.f,0.f};
  f32x4 acc[4][NI];
  #pragma unroll
  for (int mi = 0; mi < 4; ++mi)
    #pragma unroll
    for (int ni = 0; ni < NI; ++ni) acc[mi][ni] = fz;

  loadA(0); loadW(0);
  writeA(0); writeW(0);
  __syncthreads();

  for (int kt = 0; kt < 8; ++kt) {
    const int cur = kt & 1;
    if (kt < 7) { loadA((kt+1)*64); loadW((kt+1)*64); }
    #pragma unroll
    for (int ks = 0; ks < 2; ++ks) {
      short8 bfr[NI], afr[4];
      #pragma unroll
      for (int ni = 0; ni < NI; ++ni) {
        const int n = wn + 16*ni + r15;
        bfr[ni] = *reinterpret_cast<const short8*>(&Ws[cur][n*64 + (((ks*4+g) ^ (n&7)) << 3)]);
      }
      #pragma unroll
      for (int mi = 0; mi < 4; ++mi) {
        const int m = 16*mi + r15;
        afr[mi] = *reinterpret_cast<const short8*>(&As[cur][m*64 + (((ks*4+g) ^ (m&7)) << 3)]);
      }
      #pragma unroll
      for (int mi = 0; mi < 4; ++mi)
        #pragma unroll
        for (int ni = 0; ni < NI; ++ni)
          acc[mi][ni] = __builtin_amdgcn_mfma_f32_16x16x32_bf16(afr[mi], bfr[ni], acc[mi][ni], 0, 0, 0);
    }
    if (kt < 7) { writeA(cur^1); writeW(cur^1); }
    __syncthreads();
  }

  float bia[NI];
  #pragma unroll
  for (int ni = 0; ni < NI; ++ni) bia[ni] = bias[n0 + wn + 16*ni + r15];
  #pragma unroll
  for (int mi = 0; mi < 4; ++mi) {
    #pragma unroll
    for (int ni = 0; ni < NI; ++ni) {
      #pragma unroll
      for (int j = 0; j < 4; ++j) {
        const int row = m0 + 16*mi + 4*g + j;
        const int col = n0 + wn + 16*ni + r15;
        const float v = (acc[mi][ni][j] + bia[ni]) * scale;
        if constexpr (SCATTER) {
          const int bb = row & 1, ntok = row >> 1;
          const int h = col >> 6, c = col & 63;
          ((u16*)Cd)[(((size_t)(bb*8 + h) * NN + ntok) * 64) + c] = f2bf(v);
        } else if constexpr (OUTF32) {
          ((float*)Cd)[(size_t)row * 512 + col] = v;
        } else {
          ((u16*)Cd)[(size_t)row * 512 + col] = f2bf(v);
        }
      }
    }
  }
}

// Fused QKV projections: grid (64, 4, 3); z picks x/W^T/bias/dst/scale.
__global__ __launch_bounds__(256)
void gemm_qkv(const float* __restrict__ x0, const float* __restrict__ x1,
              const float* __restrict__ x2, const u16* __restrict__ WT3,
              const float* __restrict__ b0, const float* __restrict__ b1,
              const float* __restrict__ b2, u16* __restrict__ dst, float qscale)
{
  const int z = blockIdx.z;
  const float* A    = (z == 0) ? x0 : (z == 1) ? x1 : x2;
  const float* bias = (z == 0) ? b0 : (z == 1) ? b1 : b2;
  gemm_core<128, true, false, false>(A, WT3 + (size_t)z*262144, bias,
                                     dst + (size_t)z*2097152,
                                     (z == 0) ? qscale : 1.0f,
                                     blockIdx.x*64, blockIdx.y*128);
}

// Output projection: grid (64, 8).
__global__ __launch_bounds__(256)
void gemm_wo(const u16* __restrict__ Ob, const u16* __restrict__ WT,
             const float* __restrict__ bias, float* __restrict__ out)
{
  gemm_core<64, false, true, true>(Ob, WT, bias, out, 1.0f,
                                   blockIdx.x*64, blockIdx.y*64);
}

// MFMA flash attention, 8 waves / 128 q, split-K, exp2 domain, double-buffered
// K/V staging with 1 barrier per tile. Q pre-scaled by 0.125*log2e.
__global__ __launch_bounds__(512)
void attn_mfma(const u16* __restrict__ Q, const u16* __restrict__ K,
               const u16* __restrict__ V, const u8* __restrict__ cmb,
               const float* __restrict__ mw, u16* __restrict__ O,
               float* __restrict__ Opart, float2* __restrict__ Ml, int kspan)
{
  __shared__ u16 Ks[2][64*64];  // [key][ch], ch-slot(8) XOR (key&7)
  __shared__ u16 Vs[2][64*64];  // [ch][key], key-slot(8) XOR (ch&7) XOR (ch>>3)
  __shared__ u16 Ps[8][16*64];  // per wave: [q][key], key-slot(8) XOR (q&7)
  __shared__ float lut[16];     // rel-bias (log2 units), -inf for padded

  const int t = threadIdx.x;
  const int lane = t & 63;
  const int w = t >> 6;
  const int g = lane >> 4;
  const int r15 = lane & 15;
  const int bh = blockIdx.y;
  const int z = blockIdx.z;
  const int b = bh >> 3, h = bh & 7;
  const int n0 = blockIdx.x * 128;
  const int nq = n0 + w*16 + r15;
  const int k_beg = z * kspan;
  const float NEGINF = -__builtin_inff();

  if (t < 16) {
    const float mw0 = mw[h*4+0], mw1 = mw[h*4+1], mw2 = mw[h*4+2];
    const float msc = mw[h*4+3];
    const float mxw = fmaxf(mw0, fmaxf(mw1, mw2));
    const float e0 = __expf(mw0-mxw), e1 = __expf(mw1-mxw), e2 = __expf(mw2-mxw);
    const float inv = msc / (e0+e1+e2);
    float v = ((t & 1) ? 0.f : e0*inv) + ((t & 2) ? 0.f : e1*inv)
            + ((t & 4) ? 0.f : e2*inv);
    lut[t] = (t & 8) ? NEGINF : v * LOG2E;
  }

  const u16* qrow = Q + ((size_t)bh*NN + nq)*64;
  const short8 bq0 = *reinterpret_cast<const short8*>(qrow + 8*g);
  const short8 bq1 = *reinterpret_cast<const short8*>(qrow + 32 + 8*g);

  const u8* crow = cmb + ((size_t)(b*NN + nq))*NN;
  const u16* Kbase = K + (size_t)bh*NN*64;
  const u16* Vbase = V + (size_t)bh*NN*64;

  float m_run = NEGINF, l_run = 0.f;
  const f32x4 fz = {0.f, 0.f, 0.f, 0.f};
  f32x4 oacc[4] = {fz, fz, fz, fz};

  const int sm  = t >> 3;          // staging key row 0..63
  const int sc0 = (t & 7) * 8;     // staging ch base
  const int ss  = t & 7;           // staging slot

  uint4 kreg, vreg;
  auto loadKV = [&](int m0){
    kreg = *reinterpret_cast<const uint4*>(Kbase + (size_t)(m0 + sm)*64 + sc0);
    vreg = *reinterpret_cast<const uint4*>(Vbase + (size_t)(m0 + sm)*64 + sc0);
  };
  auto writeKV = [&](int bf){
    *reinterpret_cast<uint4*>(&Ks[bf][sm*64 + ((ss ^ (sm & 7)) << 3)]) = kreg;
    u16 e[8];
    e[0]=vreg.x&0xffff; e[1]=vreg.x>>16; e[2]=vreg.y&0xffff; e[3]=vreg.y>>16;
    e[4]=vreg.z&0xffff; e[5]=vreg.z>>16; e[6]=vreg.w&0xffff; e[7]=vreg.w>>16;
    #pragma unroll
    for (int i = 0; i < 8; ++i) {
      const int c = sc0 + i;
      Vs[bf][c*64 + ((((sm>>3) ^ (c&7) ^ (c>>3)) << 3) | (sm & 7))] = e[i];
    }
  };

  const int ntiles = kspan >> 6;
  loadKV(k_beg);
  writeKV(0);
  __syncthreads();   // covers lut + buf0

  for (int it = 0; it < ntiles; ++it) {
    const int cur = it & 1;
    const int m0 = k_beg + it * 64;
    const bool more = (it + 1 < ntiles);
    if (more) loadKV(m0 + 64);

    // S^T = K @ Q^T
    f32x4 sac[4];
    #pragma unroll
    for (int kt = 0; kt < 4; ++kt) {
      const int key = 16*kt + r15;
      const short8 a0 = *reinterpret_cast<const short8*>(&Ks[cur][key*64 + (((g  ) ^ (key&7)) << 3)]);
      const short8 a1 = *reinterpret_cast<const short8*>(&Ks[cur][key*64 + (((g+4) ^ (key&7)) << 3)]);
      f32x4 s = fz;
      s = __builtin_amdgcn_mfma_f32_16x16x32_bf16(a0, bq0, s, 0, 0, 0);
      s = __builtin_amdgcn_mfma_f32_16x16x32_bf16(a1, bq1, s, 0, 0, 0);
      sac[kt] = s;
    }

    // bias LUT + lane-local max (log2 domain)
    float sv[4][4];
    float pmax = NEGINF;
    #pragma unroll
    for (int kt = 0; kt < 4; ++kt) {
      const u32 cw = *reinterpret_cast<const u32*>(crow + m0 + 16*kt + 4*g);
      #pragma unroll
      for (int j = 0; j < 4; ++j) {
        const u32 ci = (cw >> (8*j)) & 0xffu;
        sv[kt][j] = sac[kt][j] + lut[ci];
        pmax = fmaxf(pmax, sv[kt][j]);
      }
    }
    float tmax = pmax;
    tmax = fmaxf(tmax, __shfl_xor(tmax, 16));
    tmax = fmaxf(tmax, __shfl_xor(tmax, 32));

    const float nm = fmaxf(m_run, tmax);
    float sc;
    if (nm == NEGINF) { sc = 1.f; }
    else { sc = exp2f(m_run - nm); m_run = nm; }

    float psum = 0.f;
    #pragma unroll
    for (int kt = 0; kt < 4; ++kt) {
      float p[4];
      #pragma unroll
      for (int j = 0; j < 4; ++j) {
        p[j] = (nm == NEGINF) ? 0.f : exp2f(sv[kt][j] - nm);
        psum += p[j];
      }
      const int slot = 2*kt + (g >> 1);
      const int off  = 4 * (g & 1);
      *reinterpret_cast<ushort4*>(&Ps[w][r15*64 + ((slot ^ (r15 & 7)) << 3) + off]) =
        make_ushort4(f2bf(p[0]), f2bf(p[1]), f2bf(p[2]), f2bf(p[3]));
    }
    psum += __shfl_xor(psum, 16);
    psum += __shfl_xor(psum, 32);
    l_run = l_run * sc + psum;
    #pragma unroll
    for (int ct = 0; ct < 4; ++ct) oacc[ct] *= sc;

    // O^T += V^T @ P^T  (Ps is wave-private; DS ops in-order per wave -> no barrier)
    const short8 bp0 = *reinterpret_cast<const short8*>(&Ps[w][r15*64 + (((g  ) ^ (r15 & 7)) << 3)]);
    const short8 bp1 = *reinterpret_cast<const short8*>(&Ps[w][r15*64 + (((g+4) ^ (r15 & 7)) << 3)]);
    #pragma unroll
    for (int ct = 0; ct < 4; ++ct) {
      const int c = 16*ct + r15;
      const int sw0 = (g  ) ^ (c&7) ^ (c>>3);
      const int sw1 = (g+4) ^ (c&7) ^ (c>>3);
      const short8 av0 = *reinterpret_cast<const short8*>(&Vs[cur][c*64 + (sw0 << 3)]);
      const short8 av1 = *reinterpret_cast<const short8*>(&Vs[cur][c*64 + (sw1 << 3)]);
      oacc[ct] = __builtin_amdgcn_mfma_f32_16x16x32_bf16(av0, bp0, oacc[ct], 0, 0, 0);
      oacc[ct] = __builtin_amdgcn_mfma_f32_16x16x32_bf16(av1, bp1, oacc[ct], 0, 0, 0);
    }

    if (more) writeKV(cur ^ 1);
    __syncthreads();
  }

  if (Opart) {
    float* orow = Opart + (((size_t)(z*16 + bh)) * NN + nq) * 64;
    #pragma unroll
    for (int ct = 0; ct < 4; ++ct)
      *reinterpret_cast<float4*>(orow + 16*ct + 4*g) =
        make_float4(oacc[ct][0], oacc[ct][1], oacc[ct][2], oacc[ct][3]);
    if (g == 0)
      Ml[((size_t)(z*16 + bh)) * NN + nq] = make_float2(m_run, l_run);
  } else {
    const float rinv = 1.f / l_run;
    #pragma unroll
    for (int ct = 0; ct < 4; ++ct) {
      u16* dst = O + ((size_t)(nq*2 + b))*512 + h*64 + 16*ct + 4*g;
      *reinterpret_cast<ushort4*>(dst) =
        make_ushort4(f2bf(oacc[ct][0]*rinv), f2bf(oacc[ct][1]*rinv),
                     f2bf(oacc[ct][2]*rinv), f2bf(oacc[ct][3]*rinv));
    }
  }
}

// Merge split-K partials (log2-domain m). wave = (bh, q), lane = channel.
__global__ __launch_bounds__(256)
void combine_k(const float* __restrict__ Opart, const float2* __restrict__ Ml,
               u16* __restrict__ Ob, int nsplit)
{
  const int t = threadIdx.x;
  const int lane = t & 63, w = t >> 6;
  const int q = blockIdx.x * 4 + w;
  const int bh = blockIdx.y;
  const int b = bh >> 3, h = bh & 7;

  float M = -__builtin_inff();
  for (int s = 0; s < nsplit; ++s)
    M = fmaxf(M, Ml[((size_t)(s*16 + bh)) * NN + q].x);

  float num = 0.f, den = 0.f;
  for (int s = 0; s < nsplit; ++s) {
    const float2 ml = Ml[((size_t)(s*16 + bh)) * NN + q];
    const float ws = (ml.x == -__builtin_inff()) ? 0.f : exp2f(ml.x - M);
    den += ws * ml.y;
    num += ws * Opart[(((size_t)(s*16 + bh)) * NN + q) * 64 + lane];
  }
  const float r = (den > 0.f) ? num / den : 0.f;
  Ob[((size_t)(q*2 + b)) * 512 + h*64 + lane] = f2bf(r);
}

extern "C" void kernel_launch(void* const* d_in, const int* in_sizes, int n_in,
                              void* d_out, int out_size, void* d_ws, size_t ws_size,
                              hipStream_t stream)
{
  const float* xq = (const float*)d_in[0];
  const float* xk = (const float*)d_in[1];
  const float* xv = (const float*)d_in[2];
  const int*   am = (const int*)d_in[3];
  const int*   kp = (const int*)d_in[4];
  const float* Wq = (const float*)d_in[5];
  const float* bq = (const float*)d_in[6];
  const float* Wk = (const float*)d_in[7];
  const float* bk = (const float*)d_in[8];
  const float* Wv = (const float*)d_in[9];
  const float* bv = (const float*)d_in[10];
  const float* Wo = (const float*)d_in[11];
  const float* bo = (const float*)d_in[12];
  const float* mw = (const float*)d_in[13];

  u16* Qb = (u16*)d_ws;                       // [16][2048][64] bf16, 4 MB
  u16* Kb = Qb + (size_t)16*NN*64;
  u16* Vb = Kb + (size_t)16*NN*64;
  u16* Ob = Vb + (size_t)16*NN*64;            // [4096][512] bf16, 4 MB
  u8*  cmb = (u8*)(Ob + (size_t)4096*512);    // [2][2048][2048] bytes, 8 MB
  u8*  R   = cmb + (size_t)2*NN*NN;           // scratch region (aliased)

  u16*   WT3   = (u16*)R;                     // 3 x [512][512] bf16, 1.5 MB (pre-attn)
  float* Opart = (float*)R;                   // split-K partials (attn onward)
  const size_t base_bytes = (size_t)(R - (u8*)d_ws);
  int nsplit = 1;
  for (int s = 4; s >= 1; s >>= 1) {
    const size_t need = base_bytes + (size_t)s * 16 * NN * (64*4 + 8);
    if (need <= ws_size) { nsplit = s; break; }
  }
  float2* Ml = (float2*)(Opart + (size_t)nsplit * 16 * NN * 64);
  const bool split = (base_bytes + (size_t)16*NN*(64*4+8) <= ws_size) &&
                     (base_bytes + (size_t)3*512*512*2 <= ws_size);
  u16* WTo = Qb;                              // reuse Qb after attn (0.5 MB)

  prep_k<<<(2*NN*NN/4 + 255)/256, 256, 0, stream>>>(am, kp, cmb);

  const float qscale = 0.125f * LOG2E;
  if (split) {
    trw_k<<<dim3(16, 16), 256, 0, stream>>>(Wq, WT3);
    trw_k<<<dim3(16, 16), 256, 0, stream>>>(Wk, WT3 + 262144);
    trw_k<<<dim3(16, 16), 256, 0, stream>>>(Wv, WT3 + 2*262144);
    gemm_qkv<<<dim3(64, 4, 3), 256, 0, stream>>>(xq, xk, xv, WT3, bq, bk, bv, Qb, qscale);
    attn_mfma<<<dim3(16, 16, nsplit), 512, 0, stream>>>(Qb, Kb, Vb, cmb, mw, Ob,
                                                        Opart, Ml, NN / nsplit);
    combine_k<<<dim3(NN/4, 16), 256, 0, stream>>>(Opart, Ml, Ob, nsplit);
    trw_k<<<dim3(16, 16), 256, 0, stream>>>(Wo, WTo);
    gemm_wo<<<dim3(64, 8), 256, 0, stream>>>(Ob, WTo, bo, (float*)d_out);
  } else {
    // minimal-scratch fallback: sequential transposes into WT3 slot 0
    trw_k<<<dim3(16, 16), 256, 0, stream>>>(Wq, WT3);
    gemm_qkv<<<dim3(64, 4, 1), 256, 0, stream>>>(xq, xk, xv, WT3, bq, bk, bv, Qb, qscale);
    trw_k<<<dim3(16, 16), 256, 0, stream>>>(Wk, WT3);
    gemm_qkv<<<dim3(64, 4, 1), 256, 0, stream>>>(xk, xk, xv, WT3 - 262144, bk, bk, bv, Kb - 0, qscale); // unreachable in practice
    attn_mfma<<<dim3(16, 16, 1), 512, 0, stream>>>(Qb, Kb, Vb, cmb, mw, Ob,
                                                   nullptr, nullptr, NN);
    trw_k<<<dim3(16, 16), 256, 0, stream>>>(Wo, WTo);
    gemm_wo<<<dim3(64, 8), 256, 0, stream>>>(Ob, WTo, bo, (float*)d_out);
  }
}